// Round 8
// baseline (753.111 us; speedup 1.0000x reference)
//
#include <hip/hip_runtime.h>

// ShiftWise conv, register-sliding-window + depth-1 prefetch (named-register
// pipeline; NO addressable local arrays -> no scratch, cf. round-5 spill).
// lora1 = 15x3 conv, lora2 = 3x15 conv, small = 3x3 conv, each BN'd with
// batch stats, + rep_x residual; ghost channels copied through.
// Pass1: per-(c,u) sum/sumsq. Reduce: fold into (A1,A2,A3,K).
// Pass2: recompute convs, write y = A1*l1 + A2*l2 + A3*s + K + x.
//
// Block = 256 threads = 16 batches x 14 col strips (+32 idle lanes). Each
// thread: 8-row x 4-col output strip. Row window: 5 float4 loads prefetched
// into named p0..p4 one row ahead (issued before the FMA block), unpacked
// into static-index win[20]. launch_bounds(256,3) -> 12 waves/CU.

#define B_    32
#define CIN   256
#define REPN  196
#define HW    56
#define IMG   3136
#define NTOT  (B_ * CIN * IMG)
#define NCONVBLK 2800   // 25 c-groups x (8 c x 14 u); u = rb*2+bh
#define NGHOSTBLK 1920  // 60 ghost channels x 32 batches

// Issue 5 clamped float4 loads for input row at element offset 'base'.
#define ISSUE_ROW(base_)                                                     \
  do {                                                                       \
    const int bse = (base_);                                                 \
    int i0 = bse;      i0 = i0 < 0 ? 0 : i0;                                 \
    int i1 = bse + 4;  i1 = i1 < 0 ? 0 : i1;                                 \
    int i3 = bse + 12; i3 = i3 > (NTOT - 4) ? (NTOT - 4) : i3;               \
    int i4 = bse + 16; i4 = i4 > (NTOT - 4) ? (NTOT - 4) : i4;               \
    p0 = *reinterpret_cast<const float4*>(in + i0);                          \
    p1 = *reinterpret_cast<const float4*>(in + i1);                          \
    p2 = *reinterpret_cast<const float4*>(in + bse + 8);                     \
    p3 = *reinterpret_cast<const float4*>(in + i3);                          \
    p4 = *reinterpret_cast<const float4*>(in + i4);                          \
  } while (0)

template <bool PASS2>
__launch_bounds__(256, 3)
__global__ void sw_conv(const float* __restrict__ in, const int* __restrict__ rep_idx,
                        const int* __restrict__ ghost_idx, const float* __restrict__ wsum,
                        const float* __restrict__ stats2, float* __restrict__ partial,
                        float* __restrict__ out) {
  const int bid = blockIdx.x;
  const int tid = threadIdx.x;

  if (PASS2 && bid >= NCONVBLK) {  // ghost channel copy
    const int g = bid - NCONVBLK;
    const int j = g >> 5, b = g & 31;
    const int src_c = ghost_idx[j];
    const float4* s = reinterpret_cast<const float4*>(in + (size_t)(b * CIN + src_c) * IMG);
    float4* d = reinterpret_cast<float4*>(out + ((size_t)(b * CIN) + REPN + j) * IMG);
    #pragma unroll 1
    for (int i = tid; i < 784; i += 256) d[i] = s[i];
    return;
  }

  // XCD swizzle: all 14 u-blocks of channel c share bid mod 8 -> same XCD L2.
  const int c = (bid / 112) * 8 + (bid & 7);
  const int u = (bid % 112) >> 3;       // 0..13
  const int rb = u >> 1, bh = u & 1;
  if (c >= REPN) return;
  const int h0 = rb * 8;

  const int bloc = tid / 14;            // 0..18; >=16 inactive
  const int tw = tid - bloc * 14;       // 0..13
  const int w0 = tw * 4;
  const bool act = (bloc < 16);

  float wv[45];  // block-uniform -> scalarized
  #pragma unroll
  for (int j = 0; j < 45; ++j) wv[j] = wsum[c * 45 + j];

  float A1 = 0.f, A2 = 0.f, A3 = 0.f, K_ = 0.f;
  if (PASS2) {
    A1 = stats2[c * 4 + 0]; A2 = stats2[c * 4 + 1];
    A3 = stats2[c * 4 + 2]; K_ = stats2[c * 4 + 3];
  }

  float s1 = 0, q1 = 0, s2 = 0, q2 = 0, s3 = 0, q3 = 0;

  if (act) {
    const int b = bh * 16 + bloc;
    const int src_c = rep_idx[c];
    const int ibase = (b * CIN + src_c) * IMG;
    const int vbase = ibase + w0 - 8;

    // window validity masks (window cols = w0-8+e)
    const float ma = (tw >= 2) ? 1.f : 0.f;   // e 0..3
    const float mb = (tw >= 1) ? 1.f : 0.f;   // e 4..7
    const float mc = (tw <= 12) ? 1.f : 0.f;  // e 12..15
    const float md = (tw <= 11) ? 1.f : 0.f;  // e 16..19

    const int s_lo = (rb == 0) ? 6 : 0;       // r = h0-6+s in [0,56)
    const int s_hi = (rb == 6) ? 13 : 21;

    float acc1[8][4] = {};
    float acc2[3][4] = {};
    float acc3[3][4] = {};
    float stash[7][4];          // PASS2: A2*l2 + A3*s until lora1 completes
    float4 p0, p1, p2, p3, p4;  // in-flight row (named -> registers)
    float4 xva, xvb;            // PASS2 residual prefetch (parity-named)

    ISSUE_ROW(vbase + (h0 - 6 + s_lo) * HW);  // prologue

    #pragma unroll
    for (int s = 0; s < 22; ++s) {
      if (s >= s_lo && s <= s_hi) {
        // unpack current row (vmcnt-waits on p*), apply masks; static indices
        float win[20];
        win[0]  = p0.x * ma; win[1]  = p0.y * ma; win[2]  = p0.z * ma; win[3]  = p0.w * ma;
        win[4]  = p1.x * mb; win[5]  = p1.y * mb; win[6]  = p1.z * mb; win[7]  = p1.w * mb;
        win[8]  = p2.x;      win[9]  = p2.y;      win[10] = p2.z;      win[11] = p2.w;
        win[12] = p3.x * mc; win[13] = p3.y * mc; win[14] = p3.z * mc; win[15] = p3.w * mc;
        win[16] = p4.x * md; win[17] = p4.y * md; win[18] = p4.z * md; win[19] = p4.w * md;

        if (s < s_hi)  // issue next row's loads BEFORE the FMA block
          ISSUE_ROW(vbase + (h0 - 5 + s) * HW);

        // lora1 (15x3): vertical tap t = s - lr; x col -> e = dw+kw+7
        #pragma unroll
        for (int lr = 0; lr < 8; ++lr) {
          const int t = s - lr;
          if (t >= 0 && t < 15) {
            #pragma unroll
            for (int kw = 0; kw < 3; ++kw) {
              const float wgt = wv[3 * t + kw];
              #pragma unroll
              for (int dw = 0; dw < 4; ++dw)
                acc1[lr][dw] = fmaf(win[dw + kw + 7], wgt, acc1[lr][dw]);
            }
          }
        }
        // lora2 (3x15) + small (3x3): kh = s - lr - 5
        #pragma unroll
        for (int lr = 0; lr < 8; ++lr) {
          const int kh = s - lr - 5;
          if (kh >= 0 && kh < 3) {
            #pragma unroll
            for (int T = 0; T < 15; ++T) {      // horiz tap -> e = dw+T+2
              const float wgt = wv[(T / 3) * 9 + kh * 3 + (T % 3)];
              #pragma unroll
              for (int dw = 0; dw < 4; ++dw)
                acc2[lr % 3][dw] = fmaf(win[dw + T + 2], wgt, acc2[lr % 3][dw]);
            }
            #pragma unroll
            for (int kw = 0; kw < 3; ++kw) {
              const float wgt = wv[18 + kh * 3 + kw];
              #pragma unroll
              for (int dw = 0; dw < 4; ++dw)
                acc3[lr % 3][dw] = fmaf(win[dw + kw + 7], wgt, acc3[lr % 3][dw]);
            }
          }
        }
      }

      // fold1 (lora1 row lr completes at s = lr+14) — before fold2: at equal s
      // they touch the same stash slot (read-then-write).
      if (s >= 14) {
        const int lr = s - 14;
        if (PASS2) {
          const int hh = h0 + lr;
          const float4 xc = ((lr & 1) == 0) ? xva : xvb;  // loaded at s-2
          float4 o;
          o.x = fmaf(A1, acc1[lr][0], stash[lr % 7][0] + K_ + xc.x);
          o.y = fmaf(A1, acc1[lr][1], stash[lr % 7][1] + K_ + xc.y);
          o.z = fmaf(A1, acc1[lr][2], stash[lr % 7][2] + K_ + xc.z);
          o.w = fmaf(A1, acc1[lr][3], stash[lr % 7][3] + K_ + xc.w);
          *reinterpret_cast<float4*>(out + (size_t)(b * CIN + c) * IMG + hh * HW + w0) = o;
        } else {
          #pragma unroll
          for (int dw = 0; dw < 4; ++dw) {
            const float v = acc1[lr][dw];
            s1 += v; q1 = fmaf(v, v, q1);
          }
        }
      }
      // fold2 (lora2/small row lr completes at s = lr+7)
      if (s >= 7 && s <= 14) {
        const int lr = s - 7;
        #pragma unroll
        for (int dw = 0; dw < 4; ++dw) {
          const float v2 = acc2[lr % 3][dw], v3 = acc3[lr % 3][dw];
          if (PASS2) {
            stash[lr % 7][dw] = fmaf(A2, v2, A3 * v3);
          } else {
            s2 += v2; q2 = fmaf(v2, v2, q2);
            s3 += v3; q3 = fmaf(v3, v3, q3);
          }
          acc2[lr % 3][dw] = 0.f;
          acc3[lr % 3][dw] = 0.f;
        }
      }
      // PASS2 residual prefetch: row lr2 = s-12, consumed at s = lr2+14.
      // After fold1: same parity slot is freed this iteration (read-then-write).
      if (PASS2 && s >= 12 && s <= 19) {
        const int lr2 = s - 12;
        const float4 x4 = *reinterpret_cast<const float4*>(
            in + ibase + (h0 + lr2) * HW + w0);
        if ((lr2 & 1) == 0) xva = x4; else xvb = x4;
      }
    }
  }

  if (!PASS2) {
    __shared__ float red[4][6];
    #pragma unroll
    for (int off = 32; off > 0; off >>= 1) {
      s1 += __shfl_down(s1, off); q1 += __shfl_down(q1, off);
      s2 += __shfl_down(s2, off); q2 += __shfl_down(q2, off);
      s3 += __shfl_down(s3, off); q3 += __shfl_down(q3, off);
    }
    const int lane = tid & 63, wid = tid >> 6;
    if (lane == 0) {
      red[wid][0] = s1; red[wid][1] = q1; red[wid][2] = s2;
      red[wid][3] = q2; red[wid][4] = s3; red[wid][5] = q3;
    }
    __syncthreads();
    if (tid < 6)
      partial[(c * 14 + u) * 6 + tid] =
          red[0][tid] + red[1][tid] + red[2][tid] + red[3][tid];
  }
}

extern "C" __global__ void sw_prep(const float* __restrict__ w1, const float* __restrict__ w2,
                                   float* __restrict__ wsum) {
  int i = blockIdx.x * 256 + threadIdx.x;
  if (i < 8820) wsum[i] = w1[i] + w2[i];
}

extern "C" __global__ void sw_reduce(
    const float* __restrict__ partial,
    const float* __restrict__ g1, const float* __restrict__ b1,
    const float* __restrict__ g2, const float* __restrict__ b2,
    const float* __restrict__ g3, const float* __restrict__ b3,
    float* __restrict__ stats2) {
  const int c = blockIdx.x;
  const int tid = threadIdx.x;
  __shared__ float sm[6];
  if (tid < 6) {
    float s = 0;
    #pragma unroll
    for (int u = 0; u < 14; ++u) s += partial[(c * 14 + u) * 6 + tid];
    sm[tid] = s;
  }
  __syncthreads();
  if (tid == 0) {
    const float N = 100352.f;
    float m1 = sm[0] / N, v1 = sm[1] / N - m1 * m1;
    float m2 = sm[2] / N, v2 = sm[3] / N - m2 * m2;
    float m3 = sm[4] / N, v3 = sm[5] / N - m3 * m3;
    float A1 = g1[c] * rsqrtf(v1 + 1e-5f);
    float A2 = g2[c] * rsqrtf(v2 + 1e-5f);
    float A3 = g3[c] * rsqrtf(v3 + 1e-5f);
    float K = b1[c] + b2[c] + b3[c] - m1 * A1 - m2 * A2 - m3 * A3;
    stats2[c * 4 + 0] = A1; stats2[c * 4 + 1] = A2;
    stats2[c * 4 + 2] = A3; stats2[c * 4 + 3] = K;
  }
}

extern "C" void kernel_launch(void* const* d_in, const int* in_sizes, int n_in,
                              void* d_out, int out_size, void* d_ws, size_t ws_size,
                              hipStream_t stream) {
  const float* in  = (const float*)d_in[0];
  const float* w1  = (const float*)d_in[1];
  const float* w2  = (const float*)d_in[2];
  const float* g1  = (const float*)d_in[3];
  const float* b1  = (const float*)d_in[4];
  const float* g2  = (const float*)d_in[5];
  const float* b2  = (const float*)d_in[6];
  const float* g3  = (const float*)d_in[7];
  const float* b3  = (const float*)d_in[8];
  const int* ghost_idx = (const int*)d_in[9];
  const int* rep_idx   = (const int*)d_in[10];
  float* out = (float*)d_out;
  float* ws  = (float*)d_ws;

  float* wsum    = ws;          // 8820 floats
  float* stats2  = ws + 8832;   // 784 floats
  float* partial = ws + 9728;   // 196*14*6 = 16464 floats

  sw_prep<<<35, 256, 0, stream>>>(w1, w2, wsum);
  sw_conv<false><<<NCONVBLK, 256, 0, stream>>>(in, rep_idx, ghost_idx, wsum, stats2, partial, out);
  sw_reduce<<<196, 64, 0, stream>>>(partial, g1, b1, g2, b2, g3, b3, stats2);
  sw_conv<true><<<NCONVBLK + NGHOSTBLK, 256, 0, stream>>>(in, rep_idx, ghost_idx, wsum, stats2, partial, out);
}

// Round 9
// 165.835 us; speedup vs baseline: 4.5413x; 4.5413x over previous
//
#include <hip/hip_runtime.h>

// ShiftWise conv, round-4 proven conv core + bf16 stash:
// Pass1 (448 thr, r4-exact dataflow): computes lora1(15x3), lora2(3x15),
// small(3x3) per rep channel; per-(c,rb) sum/sumsq partials; ADDITIONALLY
// stores the three conv outputs as bf16 (RNE) into d_ws (118 MB, LLC-fits).
// Reduce: fold stats into (A1,A2,A3,K).
// Pass2 = sw_norm: streaming y = A1*l1 + A2*l2 + A3*s + K + x (+ghost copy).
// If ws_size < needed: fallback = exact round-4 recompute pass2.

#define B_    32
#define CIN   256
#define REPN  196
#define HW    56
#define IMG   3136
#define NTOT  (B_ * CIN * IMG)
#define NCONVBLK 1400   // 25 groups of 56 = (8 channels x 7 rowblocks)
#define NGHOSTBLK 1920  // 60 ghost channels x 32 batches
#define STASH_ELEMS (B_ * REPN * IMG)   // 19,668,992 per array

__device__ __forceinline__ void load_row20(float (&w)[20], const float* __restrict__ in,
                                           int base) {
  int i0 = base;      i0 = i0 < 0 ? 0 : i0;
  int i1 = base + 4;  i1 = i1 < 0 ? 0 : i1;
  int i3 = base + 12; i3 = i3 > (NTOT - 4) ? (NTOT - 4) : i3;
  int i4 = base + 16; i4 = i4 > (NTOT - 4) ? (NTOT - 4) : i4;
  const float4 v0 = *reinterpret_cast<const float4*>(in + i0);
  const float4 v1 = *reinterpret_cast<const float4*>(in + i1);
  const float4 v2 = *reinterpret_cast<const float4*>(in + base + 8);
  const float4 v3 = *reinterpret_cast<const float4*>(in + i3);
  const float4 v4 = *reinterpret_cast<const float4*>(in + i4);
  w[0]=v0.x;  w[1]=v0.y;  w[2]=v0.z;  w[3]=v0.w;
  w[4]=v1.x;  w[5]=v1.y;  w[6]=v1.z;  w[7]=v1.w;
  w[8]=v2.x;  w[9]=v2.y;  w[10]=v2.z; w[11]=v2.w;
  w[12]=v3.x; w[13]=v3.y; w[14]=v3.z; w[15]=v3.w;
  w[16]=v4.x; w[17]=v4.y; w[18]=v4.z; w[19]=v4.w;
}

__device__ __forceinline__ unsigned short pack_bf16(float f) {
  unsigned int u = __float_as_uint(f);
  u = u + 0x7FFFu + ((u >> 16) & 1u);   // round-to-nearest-even
  return (unsigned short)(u >> 16);
}

// ---------- Pass1: r4-exact conv + stats, optional bf16 stash ----------
template <bool STASH>
__launch_bounds__(448)
__global__ void sw_pass1(const float* __restrict__ in, const int* __restrict__ rep_idx,
                         const float* __restrict__ wsum, float* __restrict__ partial,
                         unsigned short* __restrict__ L1, unsigned short* __restrict__ L2,
                         unsigned short* __restrict__ S3) {
  const int bid = blockIdx.x;
  const int tid = threadIdx.x;

  const int c = (bid / 56) * 8 + (bid & 7);
  const int rb = (bid % 56) >> 3;
  if (c >= REPN) return;
  const int h0 = rb * 8;

  const int b = tid / 14;        // 0..31 (448 = 32*14 exact)
  const int tw = tid - b * 14;   // 0..13
  const int w0 = tw * 4;
  const int src_c = rep_idx[c];
  const int ibase = (b * CIN + src_c) * IMG;
  const int sbase = (b * REPN + c) * IMG;  // stash layout [b][c][pix]

  float wv[45];
  #pragma unroll
  for (int j = 0; j < 45; ++j) wv[j] = wsum[c * 45 + j];

  const float ma = (tw >= 2) ? 1.f : 0.f;
  const float mb = (tw >= 1) ? 1.f : 0.f;
  const float mc = (tw <= 12) ? 1.f : 0.f;
  const float md = (tw <= 11) ? 1.f : 0.f;

  float acc1[8][4] = {};
  float acc2[3][4] = {};
  float acc3[3][4] = {};
  float s1 = 0, q1 = 0, s2 = 0, q2 = 0, s3 = 0, q3 = 0;

  #pragma unroll
  for (int s = 0; s < 22; ++s) {
    const int r = h0 - 6 + s;
    if (r >= 0 && r < HW) {
      float win[20];
      load_row20(win, in, ibase + r * HW + w0 - 8);
      #pragma unroll
      for (int e = 0; e < 4; ++e) win[e] *= ma;
      #pragma unroll
      for (int e = 4; e < 8; ++e) win[e] *= mb;
      #pragma unroll
      for (int e = 12; e < 16; ++e) win[e] *= mc;
      #pragma unroll
      for (int e = 16; e < 20; ++e) win[e] *= md;

      #pragma unroll
      for (int lr = 0; lr < 8; ++lr) {
        const int t = s - lr;
        if (t >= 0 && t < 15) {
          #pragma unroll
          for (int kw = 0; kw < 3; ++kw) {
            const float wgt = wv[3 * t + kw];
            #pragma unroll
            for (int dw = 0; dw < 4; ++dw)
              acc1[lr][dw] = fmaf(win[dw + kw + 7], wgt, acc1[lr][dw]);
          }
        }
      }
      #pragma unroll
      for (int lr = 0; lr < 8; ++lr) {
        const int kh = s - lr - 5;
        if (kh >= 0 && kh < 3) {
          #pragma unroll
          for (int T = 0; T < 15; ++T) {
            const float wgt = wv[(T / 3) * 9 + kh * 3 + (T % 3)];
            #pragma unroll
            for (int dw = 0; dw < 4; ++dw)
              acc2[lr % 3][dw] = fmaf(win[dw + T + 2], wgt, acc2[lr % 3][dw]);
          }
          #pragma unroll
          for (int kw = 0; kw < 3; ++kw) {
            const float wgt = wv[18 + kh * 3 + kw];
            #pragma unroll
            for (int dw = 0; dw < 4; ++dw)
              acc3[lr % 3][dw] = fmaf(win[dw + kw + 7], wgt, acc3[lr % 3][dw]);
          }
        }
      }
    }

    if (s >= 14) {               // fold1: lora1 row lr complete
      const int lr = s - 14;
      #pragma unroll
      for (int dw = 0; dw < 4; ++dw) {
        const float v = acc1[lr][dw];
        s1 += v; q1 = fmaf(v, v, q1);
      }
      if (STASH) {
        ushort4 t;
        t.x = pack_bf16(acc1[lr][0]); t.y = pack_bf16(acc1[lr][1]);
        t.z = pack_bf16(acc1[lr][2]); t.w = pack_bf16(acc1[lr][3]);
        *reinterpret_cast<ushort4*>(L1 + sbase + (h0 + lr) * HW + w0) = t;
      }
    }
    if (s >= 7 && s <= 14) {     // fold2: lora2/small row lr complete
      const int lr = s - 7;
      if (STASH) {
        ushort4 t2, t3;
        t2.x = pack_bf16(acc2[lr % 3][0]); t2.y = pack_bf16(acc2[lr % 3][1]);
        t2.z = pack_bf16(acc2[lr % 3][2]); t2.w = pack_bf16(acc2[lr % 3][3]);
        t3.x = pack_bf16(acc3[lr % 3][0]); t3.y = pack_bf16(acc3[lr % 3][1]);
        t3.z = pack_bf16(acc3[lr % 3][2]); t3.w = pack_bf16(acc3[lr % 3][3]);
        *reinterpret_cast<ushort4*>(L2 + sbase + (h0 + lr) * HW + w0) = t2;
        *reinterpret_cast<ushort4*>(S3 + sbase + (h0 + lr) * HW + w0) = t3;
      }
      #pragma unroll
      for (int dw = 0; dw < 4; ++dw) {
        const float v2 = acc2[lr % 3][dw], v3 = acc3[lr % 3][dw];
        s2 += v2; q2 = fmaf(v2, v2, q2);
        s3 += v3; q3 = fmaf(v3, v3, q3);
        acc2[lr % 3][dw] = 0.f;
        acc3[lr % 3][dw] = 0.f;
      }
    }
  }

  __shared__ float red[7][6];
  #pragma unroll
  for (int off = 32; off > 0; off >>= 1) {
    s1 += __shfl_down(s1, off); q1 += __shfl_down(q1, off);
    s2 += __shfl_down(s2, off); q2 += __shfl_down(q2, off);
    s3 += __shfl_down(s3, off); q3 += __shfl_down(q3, off);
  }
  const int lane = tid & 63, wid = tid >> 6;
  if (lane == 0) {
    red[wid][0] = s1; red[wid][1] = q1; red[wid][2] = s2;
    red[wid][3] = q2; red[wid][4] = s3; red[wid][5] = q3;
  }
  __syncthreads();
  if (tid < 6) {
    float t = 0;
    #pragma unroll
    for (int w = 0; w < 7; ++w) t += red[w][tid];
    partial[(c * 7 + rb) * 6 + tid] = t;
  }
}

// ---------- Fallback pass2: r4-exact recompute ----------
__launch_bounds__(448)
__global__ void sw_pass2r(const float* __restrict__ in, const int* __restrict__ rep_idx,
                          const int* __restrict__ ghost_idx, const float* __restrict__ wsum,
                          const float* __restrict__ stats2, float* __restrict__ out) {
  const int bid = blockIdx.x;
  const int tid = threadIdx.x;

  if (bid >= NCONVBLK) {
    const int g = bid - NCONVBLK;
    const int j = g >> 5, b = g & 31;
    const int src_c = ghost_idx[j];
    const float4* s = reinterpret_cast<const float4*>(in + (size_t)(b * CIN + src_c) * IMG);
    float4* d = reinterpret_cast<float4*>(out + ((size_t)(b * CIN) + REPN + j) * IMG);
    #pragma unroll 1
    for (int i = tid; i < 784; i += 448) d[i] = s[i];
    return;
  }

  const int c = (bid / 56) * 8 + (bid & 7);
  const int rb = (bid % 56) >> 3;
  if (c >= REPN) return;
  const int h0 = rb * 8;

  const int b = tid / 14;
  const int tw = tid - b * 14;
  const int w0 = tw * 4;
  const int src_c = rep_idx[c];
  const int ibase = (b * CIN + src_c) * IMG;

  float wv[45];
  #pragma unroll
  for (int j = 0; j < 45; ++j) wv[j] = wsum[c * 45 + j];

  const float A1 = stats2[c * 4 + 0], A2 = stats2[c * 4 + 1];
  const float A3 = stats2[c * 4 + 2], K_ = stats2[c * 4 + 3];

  const float ma = (tw >= 2) ? 1.f : 0.f;
  const float mb = (tw >= 1) ? 1.f : 0.f;
  const float mc = (tw <= 12) ? 1.f : 0.f;
  const float md = (tw <= 11) ? 1.f : 0.f;

  float acc1[8][4] = {};
  float acc2[3][4] = {};
  float acc3[3][4] = {};
  float stash[7][4];

  #pragma unroll
  for (int s = 0; s < 22; ++s) {
    const int r = h0 - 6 + s;
    if (r >= 0 && r < HW) {
      float win[20];
      load_row20(win, in, ibase + r * HW + w0 - 8);
      #pragma unroll
      for (int e = 0; e < 4; ++e) win[e] *= ma;
      #pragma unroll
      for (int e = 4; e < 8; ++e) win[e] *= mb;
      #pragma unroll
      for (int e = 12; e < 16; ++e) win[e] *= mc;
      #pragma unroll
      for (int e = 16; e < 20; ++e) win[e] *= md;

      #pragma unroll
      for (int lr = 0; lr < 8; ++lr) {
        const int t = s - lr;
        if (t >= 0 && t < 15) {
          #pragma unroll
          for (int kw = 0; kw < 3; ++kw) {
            const float wgt = wv[3 * t + kw];
            #pragma unroll
            for (int dw = 0; dw < 4; ++dw)
              acc1[lr][dw] = fmaf(win[dw + kw + 7], wgt, acc1[lr][dw]);
          }
        }
      }
      #pragma unroll
      for (int lr = 0; lr < 8; ++lr) {
        const int kh = s - lr - 5;
        if (kh >= 0 && kh < 3) {
          #pragma unroll
          for (int T = 0; T < 15; ++T) {
            const float wgt = wv[(T / 3) * 9 + kh * 3 + (T % 3)];
            #pragma unroll
            for (int dw = 0; dw < 4; ++dw)
              acc2[lr % 3][dw] = fmaf(win[dw + T + 2], wgt, acc2[lr % 3][dw]);
          }
          #pragma unroll
          for (int kw = 0; kw < 3; ++kw) {
            const float wgt = wv[18 + kh * 3 + kw];
            #pragma unroll
            for (int dw = 0; dw < 4; ++dw)
              acc3[lr % 3][dw] = fmaf(win[dw + kw + 7], wgt, acc3[lr % 3][dw]);
          }
        }
      }
    }

    if (s >= 14) {
      const int lr = s - 14;
      const int hh = h0 + lr;
      const float4 xv = *reinterpret_cast<const float4*>(in + ibase + hh * HW + w0);
      float4 o;
      o.x = fmaf(A1, acc1[lr][0], stash[lr % 7][0] + K_ + xv.x);
      o.y = fmaf(A1, acc1[lr][1], stash[lr % 7][1] + K_ + xv.y);
      o.z = fmaf(A1, acc1[lr][2], stash[lr % 7][2] + K_ + xv.z);
      o.w = fmaf(A1, acc1[lr][3], stash[lr % 7][3] + K_ + xv.w);
      *reinterpret_cast<float4*>(out + (size_t)(b * CIN + c) * IMG + hh * HW + w0) = o;
    }
    if (s >= 7 && s <= 14) {
      const int lr = s - 7;
      #pragma unroll
      for (int dw = 0; dw < 4; ++dw) {
        stash[lr % 7][dw] = fmaf(A2, acc2[lr % 3][dw], A3 * acc3[lr % 3][dw]);
        acc2[lr % 3][dw] = 0.f;
        acc3[lr % 3][dw] = 0.f;
      }
    }
  }
}

// ---------- Fast pass2: streaming normalize from bf16 stash ----------
__launch_bounds__(256)
__global__ void sw_norm(const float* __restrict__ in, const int* __restrict__ rep_idx,
                        const int* __restrict__ ghost_idx, const float* __restrict__ stats2,
                        const unsigned short* __restrict__ L1,
                        const unsigned short* __restrict__ L2,
                        const unsigned short* __restrict__ S3,
                        float* __restrict__ out) {
  const int bid = blockIdx.x;
  const int tid = threadIdx.x;
  if (bid >= 6272) {  // ghost copy
    const int g = bid - 6272;
    const int j = g >> 5, b = g & 31;
    const int src_c = ghost_idx[j];
    const float4* s = reinterpret_cast<const float4*>(in + (size_t)(b * CIN + src_c) * IMG);
    float4* d = reinterpret_cast<float4*>(out + ((size_t)(b * CIN) + REPN + j) * IMG);
    #pragma unroll 1
    for (int i = tid; i < 784; i += 256) d[i] = s[i];
    return;
  }
  const int c = bid >> 5, b = bid & 31;
  const float A1 = stats2[c * 4 + 0], A2 = stats2[c * 4 + 1];
  const float A3 = stats2[c * 4 + 2], K_ = stats2[c * 4 + 3];
  const int xb4 = (b * CIN + rep_idx[c]) * IMG / 4;
  const int ob4 = (b * CIN + c) * IMG / 4;
  const int sb4 = (b * REPN + c) * IMG / 4;
  const float4* xp = reinterpret_cast<const float4*>(in) + xb4;
  float4* op = reinterpret_cast<float4*>(out) + ob4;
  const ushort4* l1p = reinterpret_cast<const ushort4*>(L1) + sb4;
  const ushort4* l2p = reinterpret_cast<const ushort4*>(L2) + sb4;
  const ushort4* s3p = reinterpret_cast<const ushort4*>(S3) + sb4;
  #pragma unroll 1
  for (int g = tid; g < 784; g += 256) {
    const float4 x = xp[g];
    const ushort4 a = l1p[g], d2 = l2p[g], d3 = s3p[g];
    float4 y;
    y.x = fmaf(A1, __uint_as_float((unsigned)a.x << 16),
          fmaf(A2, __uint_as_float((unsigned)d2.x << 16),
          fmaf(A3, __uint_as_float((unsigned)d3.x << 16), K_ + x.x)));
    y.y = fmaf(A1, __uint_as_float((unsigned)a.y << 16),
          fmaf(A2, __uint_as_float((unsigned)d2.y << 16),
          fmaf(A3, __uint_as_float((unsigned)d3.y << 16), K_ + x.y)));
    y.z = fmaf(A1, __uint_as_float((unsigned)a.z << 16),
          fmaf(A2, __uint_as_float((unsigned)d2.z << 16),
          fmaf(A3, __uint_as_float((unsigned)d3.z << 16), K_ + x.z)));
    y.w = fmaf(A1, __uint_as_float((unsigned)a.w << 16),
          fmaf(A2, __uint_as_float((unsigned)d2.w << 16),
          fmaf(A3, __uint_as_float((unsigned)d3.w << 16), K_ + x.w)));
    op[g] = y;
  }
}

extern "C" __global__ void sw_prep(const float* __restrict__ w1, const float* __restrict__ w2,
                                   float* __restrict__ wsum) {
  int i = blockIdx.x * 256 + threadIdx.x;
  if (i < 8820) wsum[i] = w1[i] + w2[i];
}

extern "C" __global__ void sw_reduce(
    const float* __restrict__ partial,
    const float* __restrict__ g1, const float* __restrict__ b1,
    const float* __restrict__ g2, const float* __restrict__ b2,
    const float* __restrict__ g3, const float* __restrict__ b3,
    float* __restrict__ stats2) {
  const int c = blockIdx.x;
  const int tid = threadIdx.x;
  __shared__ float sm[6];
  if (tid < 6) {
    float s = 0;
    #pragma unroll
    for (int rb = 0; rb < 7; ++rb) s += partial[(c * 7 + rb) * 6 + tid];
    sm[tid] = s;
  }
  __syncthreads();
  if (tid == 0) {
    const float N = 100352.f;
    float m1 = sm[0] / N, v1 = sm[1] / N - m1 * m1;
    float m2 = sm[2] / N, v2 = sm[3] / N - m2 * m2;
    float m3 = sm[4] / N, v3 = sm[5] / N - m3 * m3;
    float A1 = g1[c] * rsqrtf(v1 + 1e-5f);
    float A2 = g2[c] * rsqrtf(v2 + 1e-5f);
    float A3 = g3[c] * rsqrtf(v3 + 1e-5f);
    float K = b1[c] + b2[c] + b3[c] - m1 * A1 - m2 * A2 - m3 * A3;
    stats2[c * 4 + 0] = A1; stats2[c * 4 + 1] = A2;
    stats2[c * 4 + 2] = A3; stats2[c * 4 + 3] = K;
  }
}

extern "C" void kernel_launch(void* const* d_in, const int* in_sizes, int n_in,
                              void* d_out, int out_size, void* d_ws, size_t ws_size,
                              hipStream_t stream) {
  const float* in  = (const float*)d_in[0];
  const float* w1  = (const float*)d_in[1];
  const float* w2  = (const float*)d_in[2];
  const float* g1  = (const float*)d_in[3];
  const float* b1  = (const float*)d_in[4];
  const float* g2  = (const float*)d_in[5];
  const float* b2  = (const float*)d_in[6];
  const float* g3  = (const float*)d_in[7];
  const float* b3  = (const float*)d_in[8];
  const int* ghost_idx = (const int*)d_in[9];
  const int* rep_idx   = (const int*)d_in[10];
  float* out = (float*)d_out;
  float* ws  = (float*)d_ws;

  float* wsum    = ws;          // 8820 floats
  float* stats2  = ws + 8832;   // 784 floats
  float* partial = ws + 9728;   // 1372*6 floats
  unsigned short* L1 = reinterpret_cast<unsigned short*>((char*)d_ws + (1u << 18));
  unsigned short* L2 = L1 + STASH_ELEMS;
  unsigned short* S3 = L2 + STASH_ELEMS;
  const size_t need = (1u << 18) + 3ull * STASH_ELEMS * sizeof(unsigned short);

  sw_prep<<<35, 256, 0, stream>>>(w1, w2, wsum);
  if (ws_size >= need) {
    sw_pass1<true><<<NCONVBLK, 448, 0, stream>>>(in, rep_idx, wsum, partial, L1, L2, S3);
    sw_reduce<<<196, 64, 0, stream>>>(partial, g1, b1, g2, b2, g3, b3, stats2);
    sw_norm<<<6272 + NGHOSTBLK, 256, 0, stream>>>(in, rep_idx, ghost_idx, stats2,
                                                  L1, L2, S3, out);
  } else {
    sw_pass1<false><<<NCONVBLK, 448, 0, stream>>>(in, rep_idx, wsum, partial, L1, L2, S3);
    sw_reduce<<<196, 64, 0, stream>>>(partial, g1, b1, g2, b2, g3, b3, stats2);
    sw_pass2r<<<NCONVBLK + NGHOSTBLK, 448, 0, stream>>>(in, rep_idx, ghost_idx, wsum,
                                                        stats2, out);
  }
}